// Round 9
// baseline (422.129 us; speedup 1.0000x reference)
//
#include <hip/hip_runtime.h>
#include <hip/hip_bf16.h>
#include <cstdint>
#include <cstddef>

#define NNODES 100000
#define NEDGES 3200000
#define NTOT   3300000   // edges + self loops
#define FIN    256
#define HH     64        // heads*hid (layer 1 out)
#define NH     8
#define C2     40
#define NEG    0.2f

// counting-sort params
#define CHUNK  8192
#define NBLK   403       // ceil(NTOT/CHUNK)
#define NBKT   391       // ceil(NNODES/256); bucket(d) = d>>8

typedef __hip_bfloat16 bf16;
typedef __attribute__((ext_vector_type(8))) short short8;
typedef __attribute__((ext_vector_type(4))) float f32x4;

// ---------------- CSR build: two-level LDS counting sort (no global atomics) ----------------

__global__ __launch_bounds__(256) void k_bhist(const int* __restrict__ ei, int* __restrict__ bhist) {
    __shared__ int h[NBKT];
    int t = threadIdx.x;
    for (int b = t; b < NBKT; b += 256) h[b] = 0;
    __syncthreads();
    int i0 = blockIdx.x * CHUNK;
    int i1 = i0 + CHUNK; if (i1 > NTOT) i1 = NTOT;
    for (int i = i0 + t; i < i1; i += 256) {
        int d = (i < NEDGES) ? ei[NEDGES + i] : (i - NEDGES);
        atomicAdd(&h[d >> 8], 1);      // LDS atomic
    }
    __syncthreads();
    for (int b = t; b < NBKT; b += 256) bhist[b * NBLK + blockIdx.x] = h[b];
}

__global__ __launch_bounds__(512) void k_bscan(int* __restrict__ bhist, int* __restrict__ bktTot) {
    __shared__ int sm[512];
    int t = threadIdx.x, b = blockIdx.x;
    int v = (t < NBLK) ? bhist[b * NBLK + t] : 0;
    sm[t] = v;
    __syncthreads();
    for (int off = 1; off < 512; off <<= 1) {
        int u = (t >= off) ? sm[t - off] : 0;
        __syncthreads();
        sm[t] += u;
        __syncthreads();
    }
    if (t < NBLK) bhist[b * NBLK + t] = sm[t] - v;   // exclusive prefix within bucket
    if (t == NBLK - 1) bktTot[b] = sm[t];
}

__global__ __launch_bounds__(512) void k_base(const int* __restrict__ bktTot, int* __restrict__ bktBase,
                                              int* __restrict__ rowptr) {
    __shared__ int sm[512];
    int t = threadIdx.x;
    int v = (t < NBKT) ? bktTot[t] : 0;
    sm[t] = v;
    __syncthreads();
    for (int off = 1; off < 512; off <<= 1) {
        int u = (t >= off) ? sm[t - off] : 0;
        __syncthreads();
        sm[t] += u;
        __syncthreads();
    }
    if (t < NBKT) bktBase[t] = sm[t] - v;
    if (t == NBKT - 1) bktBase[NBKT] = sm[t];
    if (t == 0) rowptr[NNODES] = NTOT;
}

__global__ __launch_bounds__(256) void k_scat1(const int* __restrict__ ei, const int* __restrict__ bhist,
                                               const int* __restrict__ bktBase, unsigned int* __restrict__ pb) {
    __shared__ int cur[NBKT];
    int t = threadIdx.x, blk = blockIdx.x;
    for (int b = t; b < NBKT; b += 256) cur[b] = bktBase[b] + bhist[b * NBLK + blk];
    __syncthreads();
    int i0 = blk * CHUNK;
    int i1 = i0 + CHUNK; if (i1 > NTOT) i1 = NTOT;
    for (int i = i0 + t; i < i1; i += 256) {
        int s, d;
        if (i < NEDGES) { s = ei[i]; d = ei[NEDGES + i]; }
        else            { s = d = i - NEDGES; }
        int p = atomicAdd(&cur[d >> 8], 1);   // LDS atomic
        pb[p] = ((unsigned)s << 8) | (unsigned)(d & 255);
    }
}

__global__ __launch_bounds__(256) void k_bucket(const unsigned int* __restrict__ pb,
                                                const int* __restrict__ bktBase,
                                                int* __restrict__ rowptr, int* __restrict__ esrc) {
    __shared__ int dcnt[256];
    __shared__ int sm[256];
    __shared__ int cur[256];
    int t = threadIdx.x, b = blockIdx.x;
    int base = bktBase[b], cnt = bktBase[b + 1] - base;
    dcnt[t] = 0;
    __syncthreads();
    for (int i = t; i < cnt; i += 256) atomicAdd(&dcnt[pb[base + i] & 255], 1);
    __syncthreads();
    int v = dcnt[t];
    sm[t] = v;
    __syncthreads();
    for (int off = 1; off < 256; off <<= 1) {
        int u = (t >= off) ? sm[t - off] : 0;
        __syncthreads();
        sm[t] += u;
        __syncthreads();
    }
    int ex = sm[t] - v;
    int n = (b << 8) + t;
    if (n < NNODES) rowptr[n] = base + ex;
    cur[t] = base + ex;
    __syncthreads();
    for (int i = t; i < cnt; i += 256) {
        unsigned int e = pb[base + i];
        int p = atomicAdd(&cur[e & 255], 1);  // LDS atomic
        esrc[p] = (int)(e >> 8);
    }
}

// ---------------- Layer 1 (MFMA) ----------------

// W1[256,64] f32 -> Wf bf16 in fragment order: Wf[((s*4+f)*64 + l)*8 + j] = W1[s*32+(l>>4)*8+j][16f+(l&15)]
__global__ __launch_bounds__(256) void k_wcvt(const float* __restrict__ W, bf16* __restrict__ Wf) {
    int idx = blockIdx.x * 256 + threadIdx.x;  // < 16384, exact
    int j = idx & 7, slot = idx >> 3;
    int l = slot & 63, sf = slot >> 6;
    int s = sf >> 2, f = sf & 3;
    int k = s * 32 + (l >> 4) * 8 + j;
    int c = 16 * f + (l & 15);
    Wf[idx] = __float2bfloat16(W[k * HH + c]);
}

// h1q[4][N][16](bf16) slice-major = x @ W1 via mfma; fused att dots -> as1q[4][N][2], ad[N][8]
__global__ __launch_bounds__(256) void k_gemm1(const float* __restrict__ x, const bf16* __restrict__ Wf,
                                               const float* __restrict__ asw, const float* __restrict__ adw,
                                               bf16* __restrict__ h1q, float* __restrict__ as1q,
                                               float* __restrict__ ad) {
    __shared__ short xs[64][256];   // bf16 bits, 8-elem blocks swizzled: kb' = kb ^ (row&7)
    int t = threadIdx.x;
    int n0 = blockIdx.x * 64;
    {
        int r = t >> 2, cq = t & 3;
        int n = n0 + r; if (n >= NNODES) n = NNODES - 1;   // clamp loads; stores guarded
        const float4* xr = (const float4*)(x + (size_t)n * FIN + cq * 64);
        int sw = r & 7;
#pragma unroll
        for (int u = 0; u < 8; ++u) {
            float4 p0 = xr[2 * u], p1 = xr[2 * u + 1];
            float tmp[8] = {p0.x, p0.y, p0.z, p0.w, p1.x, p1.y, p1.z, p1.w};
            short8 v;
#pragma unroll
            for (int e = 0; e < 8; ++e) {
                bf16 b = __float2bfloat16(tmp[e]);
                v[e] = *reinterpret_cast<short*>(&b);
            }
            int kb = cq * 8 + u;
            *(short8*)&xs[r][(kb ^ sw) << 3] = v;
        }
    }
    __syncthreads();
    int l = t & 63, wv = t >> 6;
    int rbase = wv * 16;
    int lr = l & 15, g = l >> 4;
    f32x4 acc[4] = {{0.f,0.f,0.f,0.f},{0.f,0.f,0.f,0.f},{0.f,0.f,0.f,0.f},{0.f,0.f,0.f,0.f}};
    const short8* wfp = (const short8*)Wf;
#pragma unroll 2
    for (int s = 0; s < 8; ++s) {
        short8 a = *(const short8*)&xs[rbase + lr][((s * 4 + g) ^ (lr & 7)) << 3];
#pragma unroll
        for (int f = 0; f < 4; ++f) {
            short8 b = wfp[(s * 4 + f) * 64 + l];
            acc[f] = __builtin_amdgcn_mfma_f32_16x16x32_bf16(a, b, acc[f], 0, 0, 0);
        }
    }
    float awf[4], dwf[4];
#pragma unroll
    for (int f = 0; f < 4; ++f) { awf[f] = asw[16 * f + lr]; dwf[f] = adw[16 * f + lr]; }
    float svv[4][4], dvv[4][4];
#pragma unroll
    for (int f = 0; f < 4; ++f) {
#pragma unroll
        for (int j = 0; j < 4; ++j) {
            float val = acc[f][j];
            int n = n0 + rbase + g * 4 + j;
            if (n < NNODES) h1q[(size_t)f * (NNODES * 16) + (size_t)n * 16 + lr] = __float2bfloat16(val);
            float sv = val * awf[f], dv = val * dwf[f];
            sv += __shfl_xor(sv, 1); sv += __shfl_xor(sv, 2); sv += __shfl_xor(sv, 4);
            dv += __shfl_xor(dv, 1); dv += __shfl_xor(dv, 2); dv += __shfl_xor(dv, 4);
            svv[f][j] = sv; dvv[f][j] = dv;
        }
    }
    if ((l & 7) == 0) {
        int hb = (l >> 3) & 1;   // head = 2f + hb
#pragma unroll
        for (int f = 0; f < 4; ++f) {
#pragma unroll
            for (int j = 0; j < 4; ++j) {
                int n = n0 + rbase + g * 4 + j;
                if (n < NNODES) {
                    as1q[(size_t)f * (NNODES * 2) + n * 2 + hb] = svv[f][j];
                    ad[n * NH + 2 * f + hb] = dvv[f][j];
                }
            }
        }
    }
}

// XCD-pinned slice aggregation: slice q = blockIdx&3 (XCD k%8 -> slice k%4, L2-resident 3.2MB slice).
// e-phase: 64 edges/lane-each, 2 heads per lane -> LDS. fma-phase: 4 edges x 16 ch per instr.
__global__ __launch_bounds__(256) void k_aggr1(const bf16* __restrict__ h1q, const float* __restrict__ as1q,
                                               const float* __restrict__ ad, const int* __restrict__ rowptr,
                                               const int* __restrict__ esrc, const float* __restrict__ b1,
                                               float* __restrict__ hmid) {
    __shared__ float wlds[4][128];
    __shared__ int   slds[4][64];
    int bid = blockIdx.x;
    int q = bid & 3, g = bid >> 2;
    int wv = threadIdx.x >> 6, t = threadIdx.x & 63;
    int n = g * 4 + wv;
    const bf16*  hq = h1q  + (size_t)q * (NNODES * 16);
    const float* aq = as1q + (size_t)q * (NNODES * 2);
    float adh0 = ad[n * NH + 2 * q];
    float adh1 = ad[n * NH + 2 * q + 1];
    int beg = __builtin_amdgcn_readfirstlane(rowptr[n]);
    int end = __builtin_amdgcn_readfirstlane(rowptr[n + 1]);
    int e4 = t >> 4, c = t & 15, hb = (t >> 3) & 1;
    float acc = 0.f, den = 0.f;
    for (int j0 = beg; j0 < end; j0 += 64) {
        int m = end - j0; if (m > 64) m = 64;
        // e-phase: lane = edge slot; one latency chain per 64 edges
        int idx = j0 + t; if (idx >= end) idx = end - 1;
        int s_t = esrc[idx];
        float2 a2 = *(const float2*)&aq[s_t * 2];
        float e0 = a2.x + adh0; e0 = (e0 > 0.f) ? e0 : NEG * e0;
        float e1 = a2.y + adh1; e1 = (e1 > 0.f) ? e1 : NEG * e1;
        bool vld = (t < m);
        float w0 = vld ? __expf(e0) : 0.f;
        float w1 = vld ? __expf(e1) : 0.f;
        slds[wv][t] = s_t;
        wlds[wv][t * 2]     = w0;
        wlds[wv][t * 2 + 1] = w1;
        __builtin_amdgcn_wave_barrier();
        // fma-phase: 4 edges per instr (lane = edge4 x ch16); 16 gathers in flight via unroll 4
        int iters = (m + 3) >> 2;
#pragma unroll 4
        for (int kk = 0; kk < iters; ++kk) {
            int eb = kk * 4 + e4;
            int se = slds[wv][eb];                 // 4 distinct, 16-lane broadcast
            float wk = wlds[wv][eb * 2 + hb];      // 8 distinct, 8-lane broadcast
            float v = __bfloat162float(hq[(size_t)se * 16 + c]);
            den += wk;
            acc = fmaf(wk, v, acc);
        }
        __builtin_amdgcn_wave_barrier();
    }
    acc += __shfl_xor(acc, 16); acc += __shfl_xor(acc, 32);
    den += __shfl_xor(den, 16); den += __shfl_xor(den, 32);
    if (t < 16) {
        float o = acc / (den + 1e-16f) + b1[q * 16 + t];
        hmid[(size_t)n * HH + q * 16 + t] = (o > 0.f) ? o : expm1f(o);  // ELU
    }
}

// ---------------- Layer 2 ----------------

// h2b[N,40](bf16) = hmid[N,64] @ W2[64,40]; also a_src2/a_dst2 [N]
__global__ __launch_bounds__(256) void k_gemm2(const float* __restrict__ hmid, const float* __restrict__ W2,
                                               const float* __restrict__ as2w, const float* __restrict__ ad2w,
                                               bf16* __restrict__ h2b, float* __restrict__ as2,
                                               float* __restrict__ ad2) {
    __shared__ float w2s[64 * C2];
    __shared__ float hrow[4][64];
    int t = threadIdx.x;
    for (int i = t; i < 64 * C2; i += 256) w2s[i] = W2[i];
    __syncthreads();
    int wv = t >> 6, ln = t & 63;
    int n = blockIdx.x * 4 + wv;
    hrow[wv][ln] = hmid[(size_t)n * HH + ln];
    __syncthreads();
    float acc = 0.f;
    if (ln < C2) {
#pragma unroll 8
        for (int k = 0; k < 64; ++k) acc = fmaf(hrow[wv][k], w2s[k * C2 + ln], acc);
    }
    float sv = 0.f, dv = 0.f;
    if (ln < C2) {
        h2b[(size_t)n * C2 + ln] = __float2bfloat16(acc);
        sv = acc * as2w[ln];
        dv = acc * ad2w[ln];
    }
#pragma unroll
    for (int off = 32; off > 0; off >>= 1) {
        sv += __shfl_xor(sv, off);
        dv += __shfl_xor(dv, off);
    }
    if (ln == 0) { as2[n] = sv; ad2[n] = dv; }
}

// one wave per node; e-phase: 64 edges (one per lane); fma-phase: s via s_load, w via readlane;
// lane t<40 owns class t; fused log_softmax
__global__ __launch_bounds__(256) void k_aggr2(const bf16* __restrict__ h2b, const float* __restrict__ as2,
                                               const float* __restrict__ ad2, const int* __restrict__ rowptr,
                                               const int* __restrict__ esrc, const float* __restrict__ b2,
                                               float* __restrict__ out) {
    int wv = threadIdx.x >> 6, t = threadIdx.x & 63;
    int n = blockIdx.x * 4 + wv;
    float adn = ad2[n];
    int beg = __builtin_amdgcn_readfirstlane(rowptr[n]);
    int end = __builtin_amdgcn_readfirstlane(rowptr[n + 1]);
    bool act = (t < C2);
    int tc = act ? t : 0;  // clamp: lanes 40..63 duplicate class 0 (discarded)
    float acc = 0.f, den_p = 0.f;
    for (int j0 = beg; j0 < end; j0 += 64) {
        int m = end - j0; if (m > 64) m = 64;
        int idx = j0 + t; if (idx >= end) idx = end - 1;
        int s_t = esrc[idx];
        float e = as2[s_t] + adn;
        e = (e > 0.f) ? e : NEG * e;
        float w_t = (t < m) ? __expf(e) : 0.f;
        den_p += w_t;
        const int* ep = esrc + j0;               // uniform address -> s_load
        int k = 0;
        for (; k + 8 <= m; k += 8) {
#pragma unroll
            for (int u = 0; u < 8; ++u) {
                int sk = __builtin_amdgcn_readfirstlane(ep[k + u]);
                float wk = __shfl(w_t, k + u);   // uniform index -> v_readlane
                acc = fmaf(wk, __bfloat162float(h2b[(size_t)sk * C2 + tc]), acc);
            }
        }
        for (; k < m; ++k) {
            int sk = __builtin_amdgcn_readfirstlane(ep[k]);
            float wk = __shfl(w_t, k);
            acc = fmaf(wk, __bfloat162float(h2b[(size_t)sk * C2 + tc]), acc);
        }
    }
    float den = den_p;
#pragma unroll
    for (int off = 32; off > 0; off >>= 1) den += __shfl_xor(den, off);
    float o = act ? (acc / (den + 1e-16f) + b2[t]) : -1e30f;
    float mx = o;
#pragma unroll
    for (int off = 32; off > 0; off >>= 1) mx = fmaxf(mx, __shfl_xor(mx, off));
    float ex = act ? __expf(o - mx) : 0.f;
    float sm = ex;
#pragma unroll
    for (int off = 32; off > 0; off >>= 1) sm += __shfl_xor(sm, off);
    if (act) out[(size_t)n * C2 + t] = o - mx - logf(sm);
}

// ---------------- launch ----------------

extern "C" void kernel_launch(void* const* d_in, const int* in_sizes, int n_in,
                              void* d_out, int out_size, void* d_ws, size_t ws_size,
                              hipStream_t stream) {
    const float* x    = (const float*)d_in[0];
    const int*   ei   = (const int*)d_in[1];
    const float* W1   = (const float*)d_in[2];
    const float* as1w = (const float*)d_in[3];
    const float* ad1w = (const float*)d_in[4];
    const float* b1   = (const float*)d_in[5];
    const float* W2   = (const float*)d_in[6];
    const float* as2w = (const float*)d_in[7];
    const float* ad2w = (const float*)d_in[8];
    const float* b2   = (const float*)d_in[9];
    float* out = (float*)d_out;

    // workspace layout; CSR temporaries alias later-written buffers (all CSR kernels
    // complete before the aliased partner is first written, same stream)
    char* ws = (char*)d_ws;
    bf16*  h1q     = (bf16*) (ws + 0);            // 12,800,000 B  [4][N][16] slice-major
    float* as1q    = (float*)(ws + 12800000);     //  3,200,000 B  [4][N][2]  slice-major
    float* ad1     = (float*)(ws + 16000000);     //  3,200,000 B  [N][8]
    float* hmid    = (float*)(ws + 19200000);     // 25,600,000 B  [N][64]
    unsigned int* pb = (unsigned int*)(ws + 19200000); // 13,200,000 B (alias hmid; dead after k_bucket)
    bf16*  h2b     = (bf16*) (ws + 44800000);     //  8,000,000 B  [N][40]
    int*   bhist   = (int*)  (ws + 44800000);     //    630,292 B (alias h2b; dead after k_scat1)
    float* as2     = (float*)(ws + 52800000);     //    400,000 B
    int*   bktBase = (int*)  (ws + 52800000);     //      1,568 B (alias as2; dead after k_bucket)
    float* ad2     = (float*)(ws + 53200000);     //    400,000 B
    int*   bktTot  = (int*)  (ws + 53200000);     //      1,564 B (alias ad2; dead after k_base)
    int*   rowp    = (int*)  (ws + 53600000);     //    400,004 B
    int*   esrc    = (int*)  (ws + 54000256);     // 13,200,000 B
    bf16*  Wf      = (bf16*) (ws + 67201024);     //     32,768 B fragment-ordered W1 -> ~67.3 MB

    k_bhist <<<NBLK, 256, 0, stream>>>(ei, bhist);
    k_bscan <<<NBKT, 512, 0, stream>>>(bhist, bktTot);
    k_base  <<<1,    512, 0, stream>>>(bktTot, bktBase, rowp);
    k_scat1 <<<NBLK, 256, 0, stream>>>(ei, bhist, bktBase, pb);
    k_bucket<<<NBKT, 256, 0, stream>>>(pb, bktBase, rowp, esrc);
    k_wcvt  <<<64, 256, 0, stream>>>(W1, Wf);
    k_gemm1 <<<(NNODES + 63) / 64, 256, 0, stream>>>(x, Wf, as1w, ad1w, h1q, as1q, ad1);
    k_aggr1 <<<NNODES, 256, 0, stream>>>(h1q, as1q, ad1, rowp, esrc, b1, hmid);
    k_gemm2 <<<NNODES / 4, 256, 0, stream>>>(hmid, W2, as2w, ad2w, h2b, as2, ad2);
    k_aggr2 <<<NNODES / 4, 256, 0, stream>>>(h2b, as2, ad2, rowp, esrc, b2, out);
}